// Round 6
// baseline (422.969 us; speedup 1.0000x reference)
//
#include <hip/hip_runtime.h>

typedef unsigned short u16;
typedef short short8 __attribute__((ext_vector_type(8)));
typedef unsigned short ushort8 __attribute__((ext_vector_type(8)));
typedef unsigned short bf16x4 __attribute__((ext_vector_type(4)));
typedef float f32x4 __attribute__((ext_vector_type(4)));

#define DEVINL __device__ __forceinline__

DEVINL float bf2f(u16 u) {
  unsigned int x = ((unsigned int)u) << 16;
  return __builtin_bit_cast(float, x);
}
DEVINL u16 f2bf(float f) {
  unsigned int x = __builtin_bit_cast(unsigned int, f);
  x += 0x7FFFu + ((x >> 16) & 1u);  // RNE
  return (u16)(x >> 16);
}

// Problem constants: B=2, S=2048, E=1024, H=16, DH=64
// r1: conv_softmax epilogue via LDS bounce -> coalesced dwordx4 (85 us).
// r2: stage-transpose static unrolled writes (75 us, VALUBusy 47->28).
// r3 (this): SC layout [h][q][k] -> [q][h][k]. Each conv block now owns a
// contiguous 64 KiB slice (read+write block-local, stream-ordered across
// blocks, write-order == read-order for L3). QK epilogue: ldc=32768,
// sCh=2048 (no coalescing change). PV A-read: lda=32768, sAh=2048.

// ---------------------------------------------------------------------------
// Fused f32 -> bf16 conversion of query + 4 weight matrices.
// ---------------------------------------------------------------------------
__global__ __launch_bounds__(256) void cvt_all(
    const float* __restrict__ q, const float* __restrict__ wq,
    const float* __restrict__ wk, const float* __restrict__ wv,
    const float* __restrict__ wo, u16* __restrict__ out) {
  int i = blockIdx.x * 256 + threadIdx.x;  // < 1048576
  const float* src;
  size_t off8;
  if (i < 524288) { src = q;  off8 = i; }
  else if (i < 655360) { src = wq; off8 = i - 524288; }
  else if (i < 786432) { src = wk; off8 = i - 655360; }
  else if (i < 917504) { src = wv; off8 = i - 786432; }
  else { src = wo; off8 = i - 917504; }
  f32x4 a = ((const f32x4*)src)[2 * off8];
  f32x4 b = ((const f32x4*)src)[2 * off8 + 1];
  ushort8 o;
#pragma unroll
  for (int e = 0; e < 4; ++e) o[e] = f2bf(a[e]);
#pragma unroll
  for (int e = 0; e < 4; ++e) o[4 + e] = f2bf(b[e]);
  ((ushort8*)out)[i] = o;
}

// ---------------------------------------------------------------------------
// NT GEMM (bf16 in via MFMA): C[i,j] = scale * sum_k A[i,k]*B[j,k] (+ bias[j])
// BK: K-tile (32 or 64). RSCALE: multiply row i of batch z by rsc[z*2048+i].
// ---------------------------------------------------------------------------
template <int BM, int BN, int BK, bool TRANSV, bool HASBIAS, bool OUTF32,
          bool RSCALE>
__global__ __launch_bounds__(256) void gemm_nt(
    const u16* __restrict__ A, const u16* __restrict__ Bm,
    const float* __restrict__ bias, void* __restrict__ C,
    const float* __restrict__ rsc,
    int K, int lda, int ldb, int ldc, float scale,
    long long sAh, long long sBh, long long sCh) {
  constexpr int LDSS = BK + 8;       // padded LDS row stride (u16)
  constexpr int KC8 = BK / 8;        // 8-elem groups per row
  constexpr int KSH = (BK == 32) ? 2 : 3;
  constexpr int WM = BM / 2, WN = BN / 2, FM = WM / 16, FN = WN / 16;
  constexpr int AIN = BM * KC8 / 256;
  constexpr int BIN = BN * KC8 / 256;

  __shared__ alignas(16) u16 As[BM * LDSS];
  __shared__ alignas(16) u16 Bs[BN * LDSS];

  const int tid = threadIdx.x;
  const int lane = tid & 63;
  const int wv = tid >> 6;
  const int wy = wv >> 1, wx = wv & 1;
  const int quad = lane >> 4, mrow = lane & 15;

  const int z = blockIdx.z;
  const u16* Ap = A + z * sAh;
  const u16* Bp = Bm + z * sBh;
  u16* Cp = (u16*)C + z * sCh;
  float* Cf = (float*)C + z * sCh;

  const int row0 = blockIdx.y * BM;
  const int col0 = blockIdx.x * BN;

  f32x4 acc[FM][FN];
#pragma unroll
  for (int i = 0; i < FM; ++i)
#pragma unroll
    for (int j = 0; j < FN; ++j) acc[i][j] = f32x4{0.f, 0.f, 0.f, 0.f};

  for (int k0 = 0; k0 < K; k0 += BK) {
    ushort8 ta[AIN], tb[BIN];
#pragma unroll
    for (int r = 0; r < AIN; ++r) {
      int idx = r * 256 + tid;
      int row = idx >> KSH, ch = idx & (KC8 - 1);
      ta[r] = *(const ushort8*)(Ap + (size_t)(row0 + row) * lda + k0 + ch * 8);
    }
#pragma unroll
    for (int r = 0; r < BIN; ++r) {
      int idx = r * 256 + tid;
      int row = idx >> KSH, ch = idx & (KC8 - 1);
      tb[r] = *(const ushort8*)(Bp + (size_t)(col0 + row) * ldb + k0 + ch * 8);
    }
    __syncthreads();  // previous iteration's LDS reads done
#pragma unroll
    for (int r = 0; r < AIN; ++r) {
      int idx = r * 256 + tid;
      int row = idx >> KSH, ch = idx & (KC8 - 1);
      *(ushort8*)&As[row * LDSS + ch * 8] = ta[r];
    }
#pragma unroll
    for (int r = 0; r < BIN; ++r) {
      int idx = r * 256 + tid;
      int row = idx >> KSH, ch = idx & (KC8 - 1);
      *(ushort8*)&Bs[row * LDSS + ch * 8] = tb[r];
    }
    __syncthreads();

#pragma unroll
    for (int ks = 0; ks < BK / 32; ++ks) {
      short8 af[FM], bfr[FN];
#pragma unroll
      for (int mi = 0; mi < FM; ++mi)
        af[mi] = *(const short8*)&As[(wy * WM + mi * 16 + mrow) * LDSS + ks * 32 + quad * 8];
#pragma unroll
      for (int ni = 0; ni < FN; ++ni)
        bfr[ni] = *(const short8*)&Bs[(wx * WN + ni * 16 + mrow) * LDSS + ks * 32 + quad * 8];
#pragma unroll
      for (int mi = 0; mi < FM; ++mi)
#pragma unroll
        for (int ni = 0; ni < FN; ++ni)
          acc[mi][ni] = __builtin_amdgcn_mfma_f32_16x16x32_bf16(
              af[mi], bfr[ni], acc[mi][ni], 0, 0, 0);
    }
  }

  // Epilogue. C/D layout: col = lane&15, row = quad*4 + r  [m89/m91 verified]
#pragma unroll
  for (int mi = 0; mi < FM; ++mi) {
    const int rowb = row0 + wy * WM + mi * 16 + quad * 4;
#pragma unroll
    for (int ni = 0; ni < FN; ++ni) {
      const int col = col0 + wx * WN + ni * 16 + mrow;
      float bv = 0.f;
      if (HASBIAS) bv = bias[col];
      f32x4 v = acc[mi][ni];
      if (OUTF32) {
#pragma unroll
        for (int r = 0; r < 4; ++r)
          Cf[(size_t)(rowb + r) * ldc + col] = v[r] * scale + bv;
      } else if (!TRANSV) {
#pragma unroll
        for (int r = 0; r < 4; ++r) {
          float rs = 1.f;
          if (RSCALE) rs = rsc[(size_t)z * 2048 + rowb + r];
          Cp[(size_t)(rowb + r) * ldc + col] = f2bf(v[r] * scale * rs + bv);
        }
      } else {
        // Ct[b][col][s], per-batch stride E*S = 2097152
        const int bb = rowb >> 11;
        const int ss = rowb & 2047;
        bf16x4 pk;
#pragma unroll
        for (int r = 0; r < 4; ++r) pk[r] = f2bf(v[r] * scale + bv);
        *(bf16x4*)(Cp + (size_t)bb * 2097152 + (size_t)col * 2048 + ss) = pk;
      }
    }
  }
}

// ---------------------------------------------------------------------------
// Fused QKV projection: A = Qb [4096 x 1024], B = Wq|Wk|Wv rows [3072 x 1024].
// col part (block-uniform, BN=128): 0 -> Qw, 1 -> Kw, 2 -> Vt (transposed
// store Vt[b][e][s]). BK=64 (16 K-iters), BM=BN=128.
// ---------------------------------------------------------------------------
__global__ __launch_bounds__(256) void gemm_qkv(
    const u16* __restrict__ A, const u16* __restrict__ Bm,
    const float* __restrict__ bq, const float* __restrict__ bk,
    const float* __restrict__ bv,
    u16* __restrict__ Qw, u16* __restrict__ Kw, u16* __restrict__ Vt) {
  constexpr int LDSS = 72;
  __shared__ alignas(16) u16 As[128 * LDSS];
  __shared__ alignas(16) u16 Bs[128 * LDSS];

  const int tid = threadIdx.x;
  const int lane = tid & 63;
  const int wv = tid >> 6;
  const int wy = wv >> 1, wx = wv & 1;
  const int quad = lane >> 4, mrow = lane & 15;

  const int row0 = blockIdx.y * 128;
  const int col0 = blockIdx.x * 128;

  f32x4 acc[4][4];
#pragma unroll
  for (int i = 0; i < 4; ++i)
#pragma unroll
    for (int j = 0; j < 4; ++j) acc[i][j] = f32x4{0.f, 0.f, 0.f, 0.f};

  for (int k0 = 0; k0 < 1024; k0 += 64) {
    ushort8 ta[4], tb[4];
#pragma unroll
    for (int r = 0; r < 4; ++r) {
      int idx = r * 256 + tid;
      int row = idx >> 3, ch = idx & 7;
      ta[r] = *(const ushort8*)(A + (size_t)(row0 + row) * 1024 + k0 + ch * 8);
      tb[r] = *(const ushort8*)(Bm + (size_t)(col0 + row) * 1024 + k0 + ch * 8);
    }
    __syncthreads();
#pragma unroll
    for (int r = 0; r < 4; ++r) {
      int idx = r * 256 + tid;
      int row = idx >> 3, ch = idx & 7;
      *(ushort8*)&As[row * LDSS + ch * 8] = ta[r];
      *(ushort8*)&Bs[row * LDSS + ch * 8] = tb[r];
    }
    __syncthreads();

#pragma unroll
    for (int ks = 0; ks < 2; ++ks) {
      short8 af[4], bfr[4];
#pragma unroll
      for (int mi = 0; mi < 4; ++mi)
        af[mi] = *(const short8*)&As[(wy * 64 + mi * 16 + mrow) * LDSS + ks * 32 + quad * 8];
#pragma unroll
      for (int ni = 0; ni < 4; ++ni)
        bfr[ni] = *(const short8*)&Bs[(wx * 64 + ni * 16 + mrow) * LDSS + ks * 32 + quad * 8];
#pragma unroll
      for (int mi = 0; mi < 4; ++mi)
#pragma unroll
        for (int ni = 0; ni < 4; ++ni)
          acc[mi][ni] = __builtin_amdgcn_mfma_f32_16x16x32_bf16(
              af[mi], bfr[ni], acc[mi][ni], 0, 0, 0);
    }
  }

  const int part = col0 >> 10;  // 0:Q 1:K 2:V (block-uniform)
  const float* bias = (part == 0) ? bq : (part == 1) ? bk : bv;
#pragma unroll
  for (int mi = 0; mi < 4; ++mi) {
    const int rowb = row0 + wy * 64 + mi * 16 + quad * 4;
#pragma unroll
    for (int ni = 0; ni < 4; ++ni) {
      const int col = col0 + wx * 64 + ni * 16 + mrow;
      const int cl = col & 1023;
      const float bvl = bias[cl];
      f32x4 v = acc[mi][ni];
      if (part == 0) {
#pragma unroll
        for (int r = 0; r < 4; ++r)
          Qw[(size_t)(rowb + r) * 1024 + cl] = f2bf(v[r] + bvl);
      } else if (part == 1) {
#pragma unroll
        for (int r = 0; r < 4; ++r)
          Kw[(size_t)(rowb + r) * 1024 + cl] = f2bf(v[r] + bvl);
      } else {
        const int bb = rowb >> 11;
        const int ss = rowb & 2047;
        bf16x4 pk;
#pragma unroll
        for (int r = 0; r < 4; ++r) pk[r] = f2bf(v[r] + bvl);
        *(bf16x4*)(Vt + (size_t)bb * 2097152 + (size_t)cl * 2048 + ss) = pk;
      }
    }
  }
}

// ---------------------------------------------------------------------------
// MFMA cross-head conv1d (KS=3, zero pad) + softmax over key axis, in place.
// SC layout [q][h][k] (r3): block q owns SC[q*32768 .. +32768) — contiguous
// 64 KiB, read and write block-local, streamed in q order across blocks.
// Writes UNNORMALIZED exp(x-M), emits 1/l to Lb (PV epilogue applies it).
// conv_b skipped: constant along softmax (k) axis -> cancels exactly.
// ---------------------------------------------------------------------------
__global__ __launch_bounds__(512, 2) void conv_softmax(
    u16* __restrict__ SC, const float* __restrict__ cw, float* __restrict__ Lb) {
  __shared__ alignas(16) u16 rawT[1026 * 24];  // 49.3 KB
  __shared__ float redA[8][16];
  __shared__ float redB[8][16];

  const int tid = threadIdx.x;
  const int lane = tid & 63;
  const int wv = tid >> 6;
  const int q = blockIdx.x;
  const int n = lane & 15;     // MFMA N-index = k-position within tile
  const int quad = lane >> 4;

  // A-frags (conv weights): lane's M-row h = n; kdim = quad*8+j -> (i,d)
  short8 a1, a2;
#pragma unroll
  for (int j = 0; j < 8; ++j) {
    const int kd = quad * 8 + j;
    const int i = kd & 15, d = kd >> 4;
    a1[j] = (short)f2bf(cw[n * 48 + i * 3 + d]);
    a2[j] = (quad < 2) ? (short)f2bf(cw[n * 48 + kd * 3 + 2]) : (short)0;
  }

  f32x4 acc[16];
#pragma unroll
  for (int ai = 0; ai < 16; ++ai) acc[ai] = f32x4{0.f, 0.f, 0.f, 0.f};

  const size_t qbase = (size_t)q * 32768;  // [q][h][k] slice base

  for (int s = 0; s < 2; ++s) {
    if (s) __syncthreads();  // all reads of previous segment done
    const int segk = s * 1024;
    {  // transpose-load segment into rawT[k-local+1][h]
      const int h = tid & 15, kc = tid >> 4;  // kc in [0,32)
      const size_t rowbase = qbase + (size_t)h * 2048 + segk;
#pragma unroll
      for (int j = 0; j < 4; ++j) {
        const int kb = kc * 32 + j * 8;
        ushort8 v = *(const ushort8*)&SC[rowbase + kb];
        u16* dst = &rawT[(kb + 1) * 24 + h];
#pragma unroll
        for (int e = 0; e < 8; ++e) dst[e * 24] = v[e];
      }
      if (tid < 32) {  // halo rows: k = segk-1 (row 0) and segk+1024 (row 1025)
        const int h2 = tid & 15;
        const int top = tid >> 4;
        const int k = segk + (top ? 1024 : -1);
        u16 val = 0;
        if ((unsigned)k < 2048u) val = SC[qbase + (size_t)h2 * 2048 + k];
        rawT[(top ? 1025 : 0) * 24 + h2] = val;
      }
    }
    __syncthreads();

#pragma unroll
    for (int tt = 0; tt < 8; ++tt) {
      const int k0l = (wv * 8 + tt) * 16;  // local k of tile start
      const short8 b1 = *(const short8*)&rawT[(k0l + n + (quad >> 1)) * 24 + (quad & 1) * 8];
      const short8 b2 = *(const short8*)&rawT[(k0l + n + 2) * 24 + (quad & 1) * 8];
      const int ai = s * 8 + tt;
      acc[ai] = __builtin_amdgcn_mfma_f32_16x16x32_bf16(a1, b1, acc[ai], 0, 0, 0);
      acc[ai] = __builtin_amdgcn_mfma_f32_16x16x32_bf16(a2, b2, acc[ai], 0, 0, 0);
    }
  }

  // ---- softmax over k per head (head = quad*4 + r) ----
  float fm[4];
#pragma unroll
  for (int r = 0; r < 4; ++r) fm[r] = -3e38f;
#pragma unroll
  for (int ai = 0; ai < 16; ++ai)
#pragma unroll
    for (int r = 0; r < 4; ++r) fm[r] = fmaxf(fm[r], acc[ai][r]);
#pragma unroll
  for (int off = 1; off < 16; off <<= 1)
#pragma unroll
    for (int r = 0; r < 4; ++r) fm[r] = fmaxf(fm[r], __shfl_xor(fm[r], off));
  if (n == 0)
#pragma unroll
    for (int r = 0; r < 4; ++r) redA[wv][quad * 4 + r] = fm[r];
  __syncthreads();
#pragma unroll
  for (int r = 0; r < 4; ++r) {
    float m = redA[0][quad * 4 + r];
#pragma unroll
    for (int w = 1; w < 8; ++w) m = fmaxf(m, redA[w][quad * 4 + r]);
    fm[r] = m;
  }
  float fs[4] = {0.f, 0.f, 0.f, 0.f};
#pragma unroll
  for (int ai = 0; ai < 16; ++ai)
#pragma unroll
    for (int r = 0; r < 4; ++r) {
      acc[ai][r] = __expf(acc[ai][r] - fm[r]);
      fs[r] += acc[ai][r];
    }
#pragma unroll
  for (int off = 1; off < 16; off <<= 1)
#pragma unroll
    for (int r = 0; r < 4; ++r) fs[r] += __shfl_xor(fs[r], off);
  if (n == 0)
#pragma unroll
    for (int r = 0; r < 4; ++r) redB[wv][quad * 4 + r] = fs[r];
  __syncthreads();
  // 1/l -> Lb (normalization applied in PV epilogue)
  if (wv == 0 && n == 0) {
#pragma unroll
    for (int r = 0; r < 4; ++r) {
      float sum = 0.f;
#pragma unroll
      for (int w = 0; w < 8; ++w) sum += redB[w][quad * 4 + r];
      Lb[(size_t)(quad * 4 + r) * 2048 + q] = 1.f / sum;
    }
  }

  // ---- write back unnormalized exp (bf16, in place), via LDS bounce ----
  // rawT is dead after the redA barrier; overlay P[h][k_local], stride 1040
  // (row dword-offset ≡ 8 mod 32), k XOR quad<<4 puts the 4 quads on 4
  // disjoint 8-bank groups -> 2 lanes/bank (free). Read applies same XOR.
  u16* Pl = rawT;
  const int hst = tid >> 5;            // store-phase head (32 thr per head)
  const int kst = (tid & 31) * 8;      // store-phase k-group base
  const int xst = (hst >> 2) << 4;     // read-side XOR = quad(h)<<4
#pragma unroll
  for (int s2 = 0; s2 < 2; ++s2) {
    if (s2) __syncthreads();           // previous segment's Pl reads done
#pragma unroll
    for (int t = 0; t < 8; ++t) {
      const int kl = (t + wv * 8) * 16 + n;
#pragma unroll
      for (int r = 0; r < 4; ++r) {
        const int h = quad * 4 + r;
        Pl[h * 1040 + (kl ^ (quad << 4))] = f2bf(acc[s2 * 8 + t][r]);
      }
    }
    __syncthreads();
#pragma unroll
    for (int p = 0; p < 4; ++p) {
      const int kg = p * 256 + kst;
      ushort8 v = *(const ushort8*)&Pl[hst * 1040 + (kg ^ xst)];
      *(ushort8*)&SC[qbase + (size_t)hst * 2048 + s2 * 1024 + kg] = v;
    }
  }
}

// Diagnostic: fill f32 output with 2000.0 (ws-too-small marker).
__global__ void fill_diag(float* out, int n) {
  int i = blockIdx.x * 256 + threadIdx.x;
  if (i < n) out[i] = 2000.0f;
}

extern "C" void kernel_launch(void* const* d_in, const int* in_sizes, int n_in,
                              void* d_out, int out_size, void* d_ws, size_t ws_size,
                              hipStream_t stream) {
  const float* query = (const float*)d_in[0];
  const float* Wq = (const float*)d_in[1];
  const float* bq = (const float*)d_in[2];
  const float* Wk = (const float*)d_in[3];
  const float* bk = (const float*)d_in[4];
  const float* Wv = (const float*)d_in[5];
  const float* bv = (const float*)d_in[6];
  const float* Wo = (const float*)d_in[7];
  const float* bo = (const float*)d_in[8];
  const float* cw = (const float*)d_in[9];
  // d_in[10] (conv_b) intentionally unused: cancels in softmax.

  const size_t SE = (size_t)4096 * 1024;  // B*S*E elems
  const size_t WE = (size_t)1024 * 1024;  // E*E elems
  const size_t SCE = (size_t)16 * 2048 * 2048;  // per-batch scores elems
  const size_t fixedB = ((SE + 4 * WE) + 4 * SE) * sizeof(u16);  // 48 MiB
  const size_t LBB = (size_t)16 * 2048 * sizeof(float);          // 128 KiB
  if (ws_size < fixedB + SCE * sizeof(u16) + LBB) {
    fill_diag<<<dim3((out_size + 255) / 256), dim3(256), 0, stream>>>(
        (float*)d_out, out_size);
    return;
  }

  u16* ws = (u16*)d_ws;
  u16* Qb = ws;              // bf16 query [b][s][e]
  u16* Wqb = Qb + SE;        // bf16 weights (contiguous: Wq|Wk|Wv|Wo)
  u16* Wkb = Wqb + WE;
  u16* Wvb = Wkb + WE;
  u16* Wob = Wvb + WE;
  u16* Qw = Wob + WE;        // [b][s][e]
  u16* Kw = Qw + SE;         // [b][s][e]
  u16* Vt = Kw + SE;         // [b][e][s] transposed V
  u16* At = Vt + SE;         // attention output [b][s][e] (bf16)
  u16* SC = At + SE;         // scores (one batch) [q][h][k]  (r3 layout)
  float* Lb = (float*)(SC + SCE);  // inverse softmax sums [h][q]

  dim3 blk(256);
  cvt_all<<<dim3(4096), blk, 0, stream>>>(query, Wq, Wk, Wv, Wo, Qb);

  // Fused Q/K/V projection (BK=64): B rows = Wqb|Wkb|Wvb (3072 x 1024)
  gemm_qkv<<<dim3(24, 32, 1), blk, 0, stream>>>(
      Qb, Wqb, bq, bk, bv, Qw, Kw, Vt);

  for (int b = 0; b < 2; ++b) {
    const size_t bQK = (size_t)b * 2097152;
    // raw scores = Q Kh^T / 8 per head: M=N=2048, K=64.
    // C layout [q][h][k]: ldc=32768, head stride sCh=2048.
    gemm_nt<128, 128, 64, false, false, false, false>
        <<<dim3(16, 16, 16), blk, 0, stream>>>(
            Qw + bQK, Kw + bQK, nullptr, SC, nullptr,
            64, 1024, 1024, 32768, 0.125f, 64LL, 64LL, 2048LL);
    // conv + softmax (unnormalized P + 1/l into Lb), [q][h][k] in place
    conv_softmax<<<dim3(2048), dim3(512), 0, stream>>>(SC, cw, Lb);
    // PV: M=2048 (q), N=64 (d), K=2048 per head; A = P [q][h][k]:
    // lda=32768, head stride sAh=2048. Epilogue applies 1/l.
    gemm_nt<64, 64, 64, false, false, false, true>
        <<<dim3(1, 32, 16), blk, 0, stream>>>(
            SC, Vt + bQK, nullptr, At + bQK, Lb,
            2048, 32768, 2048, 1024, 1.f, 2048LL, 131072LL, 64LL);
  }

  // output projection (BK=64) -> f32 d_out
  gemm_nt<128, 128, 64, false, true, true, false><<<dim3(8, 32, 1), blk, 0, stream>>>(
      At, Wob, bo, d_out, nullptr, 1024, 1024, 1024, 1024, 1.f, 0, 0, 0);
}

// Round 9
// 411.647 us; speedup vs baseline: 1.0275x; 1.0275x over previous
//
#include <hip/hip_runtime.h>

typedef unsigned short u16;
typedef unsigned int u32;
typedef short short8 __attribute__((ext_vector_type(8)));
typedef unsigned short ushort8 __attribute__((ext_vector_type(8)));
typedef unsigned short bf16x4 __attribute__((ext_vector_type(4)));
typedef float f32x4 __attribute__((ext_vector_type(4)));

#define DEVINL __device__ __forceinline__

DEVINL float bf2f(u16 u) {
  unsigned int x = ((unsigned int)u) << 16;
  return __builtin_bit_cast(float, x);
}
DEVINL u16 f2bf(float f) {
  unsigned int x = __builtin_bit_cast(unsigned int, f);
  x += 0x7FFFu + ((x >> 16) & 1u);  // RNE
  return (u16)(x >> 16);
}

// Async global->LDS, 16B per lane. LDS dest must be the WAVE-UNIFORM base
// (HW adds lane*16). Global src is per-lane.
DEVINL void ld16_lds(const u16* g, u16* l) {
  __builtin_amdgcn_global_load_lds(
      (const __attribute__((address_space(1))) u32*)(const void*)g,
      (__attribute__((address_space(3))) u32*)(void*)l, 16, 0, 0);
}

// Problem constants: B=2, S=2048, E=1024, H=16, DH=64
// r1: conv_softmax epilogue via LDS bounce -> coalesced dwordx4 (85 us).
// r2: stage-transpose static unrolled writes (75 us, VALUBusy 47->28).
// r3: [q][h][k] SC layout — REVERTED (neutral on conv, -7us on QK/PV).
// r4 (this): gemm_qkv staging via global_load_lds width=16, linear LDS
// [128][64] + XOR swizzle byte^=((row&7)<<4) (inverse-swz source, swz read).

// ---------------------------------------------------------------------------
// Fused f32 -> bf16 conversion of query + 4 weight matrices.
// ---------------------------------------------------------------------------
__global__ __launch_bounds__(256) void cvt_all(
    const float* __restrict__ q, const float* __restrict__ wq,
    const float* __restrict__ wk, const float* __restrict__ wv,
    const float* __restrict__ wo, u16* __restrict__ out) {
  int i = blockIdx.x * 256 + threadIdx.x;  // < 1048576
  const float* src;
  size_t off8;
  if (i < 524288) { src = q;  off8 = i; }
  else if (i < 655360) { src = wq; off8 = i - 524288; }
  else if (i < 786432) { src = wk; off8 = i - 655360; }
  else if (i < 917504) { src = wv; off8 = i - 786432; }
  else { src = wo; off8 = i - 917504; }
  f32x4 a = ((const f32x4*)src)[2 * off8];
  f32x4 b = ((const f32x4*)src)[2 * off8 + 1];
  ushort8 o;
#pragma unroll
  for (int e = 0; e < 4; ++e) o[e] = f2bf(a[e]);
#pragma unroll
  for (int e = 0; e < 4; ++e) o[4 + e] = f2bf(b[e]);
  ((ushort8*)out)[i] = o;
}

// ---------------------------------------------------------------------------
// NT GEMM (bf16 in via MFMA): C[i,j] = scale * sum_k A[i,k]*B[j,k] (+ bias[j])
// BK: K-tile (32 or 64). RSCALE: multiply row i of batch z by rsc[z*2048+i].
// ---------------------------------------------------------------------------
template <int BM, int BN, int BK, bool TRANSV, bool HASBIAS, bool OUTF32,
          bool RSCALE>
__global__ __launch_bounds__(256) void gemm_nt(
    const u16* __restrict__ A, const u16* __restrict__ Bm,
    const float* __restrict__ bias, void* __restrict__ C,
    const float* __restrict__ rsc,
    int K, int lda, int ldb, int ldc, float scale,
    long long sAh, long long sBh, long long sCh) {
  constexpr int LDSS = BK + 8;       // padded LDS row stride (u16)
  constexpr int KC8 = BK / 8;        // 8-elem groups per row
  constexpr int KSH = (BK == 32) ? 2 : 3;
  constexpr int WM = BM / 2, WN = BN / 2, FM = WM / 16, FN = WN / 16;
  constexpr int AIN = BM * KC8 / 256;
  constexpr int BIN = BN * KC8 / 256;

  __shared__ alignas(16) u16 As[BM * LDSS];
  __shared__ alignas(16) u16 Bs[BN * LDSS];

  const int tid = threadIdx.x;
  const int lane = tid & 63;
  const int wv = tid >> 6;
  const int wy = wv >> 1, wx = wv & 1;
  const int quad = lane >> 4, mrow = lane & 15;

  const int z = blockIdx.z;
  const u16* Ap = A + z * sAh;
  const u16* Bp = Bm + z * sBh;
  u16* Cp = (u16*)C + z * sCh;
  float* Cf = (float*)C + z * sCh;

  const int row0 = blockIdx.y * BM;
  const int col0 = blockIdx.x * BN;

  f32x4 acc[FM][FN];
#pragma unroll
  for (int i = 0; i < FM; ++i)
#pragma unroll
    for (int j = 0; j < FN; ++j) acc[i][j] = f32x4{0.f, 0.f, 0.f, 0.f};

  for (int k0 = 0; k0 < K; k0 += BK) {
    ushort8 ta[AIN], tb[BIN];
#pragma unroll
    for (int r = 0; r < AIN; ++r) {
      int idx = r * 256 + tid;
      int row = idx >> KSH, ch = idx & (KC8 - 1);
      ta[r] = *(const ushort8*)(Ap + (size_t)(row0 + row) * lda + k0 + ch * 8);
    }
#pragma unroll
    for (int r = 0; r < BIN; ++r) {
      int idx = r * 256 + tid;
      int row = idx >> KSH, ch = idx & (KC8 - 1);
      tb[r] = *(const ushort8*)(Bp + (size_t)(col0 + row) * ldb + k0 + ch * 8);
    }
    __syncthreads();  // previous iteration's LDS reads done
#pragma unroll
    for (int r = 0; r < AIN; ++r) {
      int idx = r * 256 + tid;
      int row = idx >> KSH, ch = idx & (KC8 - 1);
      *(ushort8*)&As[row * LDSS + ch * 8] = ta[r];
    }
#pragma unroll
    for (int r = 0; r < BIN; ++r) {
      int idx = r * 256 + tid;
      int row = idx >> KSH, ch = idx & (KC8 - 1);
      *(ushort8*)&Bs[row * LDSS + ch * 8] = tb[r];
    }
    __syncthreads();

#pragma unroll
    for (int ks = 0; ks < BK / 32; ++ks) {
      short8 af[FM], bfr[FN];
#pragma unroll
      for (int mi = 0; mi < FM; ++mi)
        af[mi] = *(const short8*)&As[(wy * WM + mi * 16 + mrow) * LDSS + ks * 32 + quad * 8];
#pragma unroll
      for (int ni = 0; ni < FN; ++ni)
        bfr[ni] = *(const short8*)&Bs[(wx * WN + ni * 16 + mrow) * LDSS + ks * 32 + quad * 8];
#pragma unroll
      for (int mi = 0; mi < FM; ++mi)
#pragma unroll
        for (int ni = 0; ni < FN; ++ni)
          acc[mi][ni] = __builtin_amdgcn_mfma_f32_16x16x32_bf16(
              af[mi], bfr[ni], acc[mi][ni], 0, 0, 0);
    }
  }

  // Epilogue. C/D layout: col = lane&15, row = quad*4 + r  [m89/m91 verified]
#pragma unroll
  for (int mi = 0; mi < FM; ++mi) {
    const int rowb = row0 + wy * WM + mi * 16 + quad * 4;
#pragma unroll
    for (int ni = 0; ni < FN; ++ni) {
      const int col = col0 + wx * WN + ni * 16 + mrow;
      float bv = 0.f;
      if (HASBIAS) bv = bias[col];
      f32x4 v = acc[mi][ni];
      if (OUTF32) {
#pragma unroll
        for (int r = 0; r < 4; ++r)
          Cf[(size_t)(rowb + r) * ldc + col] = v[r] * scale + bv;
      } else if (!TRANSV) {
#pragma unroll
        for (int r = 0; r < 4; ++r) {
          float rs = 1.f;
          if (RSCALE) rs = rsc[(size_t)z * 2048 + rowb + r];
          Cp[(size_t)(rowb + r) * ldc + col] = f2bf(v[r] * scale * rs + bv);
        }
      } else {
        // Ct[b][col][s], per-batch stride E*S = 2097152
        const int bb = rowb >> 11;
        const int ss = rowb & 2047;
        bf16x4 pk;
#pragma unroll
        for (int r = 0; r < 4; ++r) pk[r] = f2bf(v[r] * scale + bv);
        *(bf16x4*)(Cp + (size_t)bb * 2097152 + (size_t)col * 2048 + ss) = pk;
      }
    }
  }
}

// ---------------------------------------------------------------------------
// Fused QKV projection: A = Qb [4096 x 1024], B = Wq|Wk|Wv rows [3072 x 1024].
// col part (block-uniform, BN=128): 0 -> Qw, 1 -> Kw, 2 -> Vt (transposed
// store Vt[b][e][s]). BK=64, BM=BN=128.
// r4: staging via global_load_lds (16B/lane), linear LDS [128][64] u16 with
// XOR swizzle: LDS 16B-slot s of row r holds global col-bytes (s^(r&7))*16;
// read applies byte ^= ((row&7)<<4). Same involution both sides (rule #21).
// ---------------------------------------------------------------------------
__global__ __launch_bounds__(256) void gemm_qkv(
    const u16* __restrict__ A, const u16* __restrict__ Bm,
    const float* __restrict__ bq, const float* __restrict__ bk,
    const float* __restrict__ bv,
    u16* __restrict__ Qw, u16* __restrict__ Kw, u16* __restrict__ Vt) {
  __shared__ alignas(16) u16 As[128 * 64];
  __shared__ alignas(16) u16 Bs[128 * 64];

  const int tid = threadIdx.x;
  const int lane = tid & 63;
  const int wv = tid >> 6;           // wave 0..3
  const int wy = wv >> 1, wx = wv & 1;
  const int quad = lane >> 4, mrow = lane & 15;

  const int row0 = blockIdx.y * 128;
  const int col0 = blockIdx.x * 128;

  // staging geometry: chunk = 1 KiB = 8 rows; lane covers (row srow, slot)
  const int srow = lane >> 3;                    // 0..7 within chunk
  const int scol = ((lane & 7) ^ srow) << 4;     // inverse-swizzled byte col

  f32x4 acc[4][4];
#pragma unroll
  for (int i = 0; i < 4; ++i)
#pragma unroll
    for (int j = 0; j < 4; ++j) acc[i][j] = f32x4{0.f, 0.f, 0.f, 0.f};

  for (int k0 = 0; k0 < 1024; k0 += 64) {
    __syncthreads();  // previous iteration's LDS reads done
#pragma unroll
    for (int i = 0; i < 4; ++i) {
      const int chunk = i * 4 + wv;              // 0..15
      const int row = chunk * 8 + srow;
      ld16_lds(A + (size_t)(row0 + row) * 1024 + k0 + (scol >> 1),
               &As[chunk * 512]);
      ld16_lds(Bm + (size_t)(col0 + row) * 1024 + k0 + (scol >> 1),
               &Bs[chunk * 512]);
    }
    __syncthreads();  // drains vmcnt(0): staged data visible

#pragma unroll
    for (int ks = 0; ks < 2; ++ks) {
      short8 af[4], bfr[4];
      const int cb = ks * 64 + quad * 16;        // byte col of frag
#pragma unroll
      for (int mi = 0; mi < 4; ++mi) {
        const int rowA = wy * 64 + mi * 16 + mrow;
        af[mi] = *(const short8*)&As[rowA * 64 + ((cb ^ ((rowA & 7) << 4)) >> 1)];
      }
#pragma unroll
      for (int ni = 0; ni < 4; ++ni) {
        const int rowB = wx * 64 + ni * 16 + mrow;
        bfr[ni] = *(const short8*)&Bs[rowB * 64 + ((cb ^ ((rowB & 7) << 4)) >> 1)];
      }
#pragma unroll
      for (int mi = 0; mi < 4; ++mi)
#pragma unroll
        for (int ni = 0; ni < 4; ++ni)
          acc[mi][ni] = __builtin_amdgcn_mfma_f32_16x16x32_bf16(
              af[mi], bfr[ni], acc[mi][ni], 0, 0, 0);
    }
  }

  const int part = col0 >> 10;  // 0:Q 1:K 2:V (block-uniform)
  const float* bias = (part == 0) ? bq : (part == 1) ? bk : bv;
#pragma unroll
  for (int mi = 0; mi < 4; ++mi) {
    const int rowb = row0 + wy * 64 + mi * 16 + quad * 4;
#pragma unroll
    for (int ni = 0; ni < 4; ++ni) {
      const int col = col0 + wx * 64 + ni * 16 + mrow;
      const int cl = col & 1023;
      const float bvl = bias[cl];
      f32x4 v = acc[mi][ni];
      if (part == 0) {
#pragma unroll
        for (int r = 0; r < 4; ++r)
          Qw[(size_t)(rowb + r) * 1024 + cl] = f2bf(v[r] + bvl);
      } else if (part == 1) {
#pragma unroll
        for (int r = 0; r < 4; ++r)
          Kw[(size_t)(rowb + r) * 1024 + cl] = f2bf(v[r] + bvl);
      } else {
        const int bb = rowb >> 11;
        const int ss = rowb & 2047;
        bf16x4 pk;
#pragma unroll
        for (int r = 0; r < 4; ++r) pk[r] = f2bf(v[r] + bvl);
        *(bf16x4*)(Vt + (size_t)bb * 2097152 + (size_t)cl * 2048 + ss) = pk;
      }
    }
  }
}

// ---------------------------------------------------------------------------
// MFMA cross-head conv1d (KS=3, zero pad) + softmax over key axis, in place.
// SC layout [h][q][k]. Writes UNNORMALIZED exp(x-M), emits 1/l to Lb.
// conv_b skipped: constant along softmax (k) axis -> cancels exactly.
// r1: writeback via LDS bounce; r2: static transpose-stage writes.
// ---------------------------------------------------------------------------
__global__ __launch_bounds__(512, 2) void conv_softmax(
    u16* __restrict__ SC, const float* __restrict__ cw, float* __restrict__ Lb) {
  __shared__ alignas(16) u16 rawT[1026 * 24];  // 49.3 KB
  __shared__ float redA[8][16];
  __shared__ float redB[8][16];

  const int tid = threadIdx.x;
  const int lane = tid & 63;
  const int wv = tid >> 6;
  const int q = blockIdx.x;
  const int n = lane & 15;     // MFMA N-index = k-position within tile
  const int quad = lane >> 4;

  // A-frags (conv weights): lane's M-row h = n; kdim = quad*8+j -> (i,d)
  short8 a1, a2;
#pragma unroll
  for (int j = 0; j < 8; ++j) {
    const int kd = quad * 8 + j;
    const int i = kd & 15, d = kd >> 4;
    a1[j] = (short)f2bf(cw[n * 48 + i * 3 + d]);
    a2[j] = (quad < 2) ? (short)f2bf(cw[n * 48 + kd * 3 + 2]) : (short)0;
  }

  f32x4 acc[16];
#pragma unroll
  for (int ai = 0; ai < 16; ++ai) acc[ai] = f32x4{0.f, 0.f, 0.f, 0.f};

  for (int s = 0; s < 2; ++s) {
    if (s) __syncthreads();  // all reads of previous segment done
    const int segk = s * 1024;
    {  // transpose-load segment into rawT[k-local+1][h]
      const int h = tid & 15, kc = tid >> 4;  // kc in [0,32)
      const size_t rowbase = ((size_t)h * 2048 + q) * 2048 + segk;
#pragma unroll
      for (int j = 0; j < 4; ++j) {
        const int kb = kc * 32 + j * 8;
        ushort8 v = *(const ushort8*)&SC[rowbase + kb];
        u16* dst = &rawT[(kb + 1) * 24 + h];
#pragma unroll
        for (int e = 0; e < 8; ++e) dst[e * 24] = v[e];
      }
      if (tid < 32) {  // halo rows: k = segk-1 (row 0) and segk+1024 (row 1025)
        const int h2 = tid & 15;
        const int top = tid >> 4;
        const int k = segk + (top ? 1024 : -1);
        u16 val = 0;
        if ((unsigned)k < 2048u) val = SC[((size_t)h2 * 2048 + q) * 2048 + k];
        rawT[(top ? 1025 : 0) * 24 + h2] = val;
      }
    }
    __syncthreads();

#pragma unroll
    for (int tt = 0; tt < 8; ++tt) {
      const int k0l = (wv * 8 + tt) * 16;  // local k of tile start
      const short8 b1 = *(const short8*)&rawT[(k0l + n + (quad >> 1)) * 24 + (quad & 1) * 8];
      const short8 b2 = *(const short8*)&rawT[(k0l + n + 2) * 24 + (quad & 1) * 8];
      const int ai = s * 8 + tt;
      acc[ai] = __builtin_amdgcn_mfma_f32_16x16x32_bf16(a1, b1, acc[ai], 0, 0, 0);
      acc[ai] = __builtin_amdgcn_mfma_f32_16x16x32_bf16(a2, b2, acc[ai], 0, 0, 0);
    }
  }

  // ---- softmax over k per head (head = quad*4 + r) ----
  float fm[4];
#pragma unroll
  for (int r = 0; r < 4; ++r) fm[r] = -3e38f;
#pragma unroll
  for (int ai = 0; ai < 16; ++ai)
#pragma unroll
    for (int r = 0; r < 4; ++r) fm[r] = fmaxf(fm[r], acc[ai][r]);
#pragma unroll
  for (int off = 1; off < 16; off <<= 1)
#pragma unroll
    for (int r = 0; r < 4; ++r) fm[r] = fmaxf(fm[r], __shfl_xor(fm[r], off));
  if (n == 0)
#pragma unroll
    for (int r = 0; r < 4; ++r) redA[wv][quad * 4 + r] = fm[r];
  __syncthreads();
#pragma unroll
  for (int r = 0; r < 4; ++r) {
    float m = redA[0][quad * 4 + r];
#pragma unroll
    for (int w = 1; w < 8; ++w) m = fmaxf(m, redA[w][quad * 4 + r]);
    fm[r] = m;
  }
  float fs[4] = {0.f, 0.f, 0.f, 0.f};
#pragma unroll
  for (int ai = 0; ai < 16; ++ai)
#pragma unroll
    for (int r = 0; r < 4; ++r) {
      acc[ai][r] = __expf(acc[ai][r] - fm[r]);
      fs[r] += acc[ai][r];
    }
#pragma unroll
  for (int off = 1; off < 16; off <<= 1)
#pragma unroll
    for (int r = 0; r < 4; ++r) fs[r] += __shfl_xor(fs[r], off);
  if (n == 0)
#pragma unroll
    for (int r = 0; r < 4; ++r) redB[wv][quad * 4 + r] = fs[r];
  __syncthreads();
  // 1/l -> Lb (normalization applied in PV epilogue)
  if (wv == 0 && n == 0) {
#pragma unroll
    for (int r = 0; r < 4; ++r) {
      float sum = 0.f;
#pragma unroll
      for (int w = 0; w < 8; ++w) sum += redB[w][quad * 4 + r];
      Lb[(size_t)(quad * 4 + r) * 2048 + q] = 1.f / sum;
    }
  }

  // ---- write back unnormalized exp (bf16, in place), via LDS bounce ----
  // rawT is dead after the redA barrier; overlay P[h][k_local], stride 1040
  // (row dword-offset ≡ 8 mod 32), k XOR quad<<4 puts the 4 quads on 4
  // disjoint 8-bank groups -> 2 lanes/bank (free). Read applies same XOR.
  u16* Pl = rawT;
  const int hst = tid >> 5;            // store-phase head (32 thr per head)
  const int kst = (tid & 31) * 8;      // store-phase k-group base
  const int xst = (hst >> 2) << 4;     // read-side XOR = quad(h)<<4
#pragma unroll
  for (int s2 = 0; s2 < 2; ++s2) {
    if (s2) __syncthreads();           // previous segment's Pl reads done
#pragma unroll
    for (int t = 0; t < 8; ++t) {
      const int kl = (t + wv * 8) * 16 + n;
#pragma unroll
      for (int r = 0; r < 4; ++r) {
        const int h = quad * 4 + r;
        Pl[h * 1040 + (kl ^ (quad << 4))] = f2bf(acc[s2 * 8 + t][r]);
      }
    }
    __syncthreads();
#pragma unroll
    for (int p = 0; p < 4; ++p) {
      const int kg = p * 256 + kst;
      ushort8 v = *(const ushort8*)&Pl[hst * 1040 + (kg ^ xst)];
      *(ushort8*)&SC[((size_t)hst * 2048 + q) * 2048 + s2 * 1024 + kg] = v;
    }
  }
}

// Diagnostic: fill f32 output with 2000.0 (ws-too-small marker).
__global__ void fill_diag(float* out, int n) {
  int i = blockIdx.x * 256 + threadIdx.x;
  if (i < n) out[i] = 2000.0f;
}

extern "C" void kernel_launch(void* const* d_in, const int* in_sizes, int n_in,
                              void* d_out, int out_size, void* d_ws, size_t ws_size,
                              hipStream_t stream) {
  const float* query = (const float*)d_in[0];
  const float* Wq = (const float*)d_in[1];
  const float* bq = (const float*)d_in[2];
  const float* Wk = (const float*)d_in[3];
  const float* bk = (const float*)d_in[4];
  const float* Wv = (const float*)d_in[5];
  const float* bv = (const float*)d_in[6];
  const float* Wo = (const float*)d_in[7];
  const float* bo = (const float*)d_in[8];
  const float* cw = (const float*)d_in[9];
  // d_in[10] (conv_b) intentionally unused: cancels in softmax.

  const size_t SE = (size_t)4096 * 1024;  // B*S*E elems
  const size_t WE = (size_t)1024 * 1024;  // E*E elems
  const size_t SCE = (size_t)16 * 2048 * 2048;  // per-batch scores elems
  const size_t fixedB = ((SE + 4 * WE) + 4 * SE) * sizeof(u16);  // 48 MiB
  const size_t LBB = (size_t)16 * 2048 * sizeof(float);          // 128 KiB
  if (ws_size < fixedB + SCE * sizeof(u16) + LBB) {
    fill_diag<<<dim3((out_size + 255) / 256), dim3(256), 0, stream>>>(
        (float*)d_out, out_size);
    return;
  }

  u16* ws = (u16*)d_ws;
  u16* Qb = ws;              // bf16 query [b][s][e]
  u16* Wqb = Qb + SE;        // bf16 weights (contiguous: Wq|Wk|Wv|Wo)
  u16* Wkb = Wqb + WE;
  u16* Wvb = Wkb + WE;
  u16* Wob = Wvb + WE;
  u16* Qw = Wob + WE;        // [b][s][e]
  u16* Kw = Qw + SE;         // [b][s][e]
  u16* Vt = Kw + SE;         // [b][e][s] transposed V
  u16* At = Vt + SE;         // attention output [b][s][e] (bf16)
  u16* SC = At + SE;         // scores (one batch) [h][q][k]
  float* Lb = (float*)(SC + SCE);  // inverse softmax sums [h][q]

  dim3 blk(256);
  cvt_all<<<dim3(4096), blk, 0, stream>>>(query, Wq, Wk, Wv, Wo, Qb);

  // Fused Q/K/V projection (BK=64): B rows = Wqb|Wkb|Wvb (3072 x 1024)
  gemm_qkv<<<dim3(24, 32, 1), blk, 0, stream>>>(
      Qb, Wqb, bq, bk, bv, Qw, Kw, Vt);

  for (int b = 0; b < 2; ++b) {
    const size_t bQK = (size_t)b * 2097152;
    // raw scores = Q Kh^T / 8 per head: M=N=2048, K=64 (BK=64, single stage)
    gemm_nt<128, 128, 64, false, false, false, false>
        <<<dim3(16, 16, 16), blk, 0, stream>>>(
            Qw + bQK, Kw + bQK, nullptr, SC, nullptr,
            64, 1024, 1024, 2048, 0.125f, 64LL, 64LL, 4194304LL);
    // conv + softmax (unnormalized P + 1/l into Lb)
    conv_softmax<<<dim3(2048), dim3(512), 0, stream>>>(SC, cw, Lb);
    // PV: M=2048 (q), N=64 (d), K=2048 per head (BK=64); epilogue applies 1/l
    gemm_nt<64, 64, 64, false, false, false, true>
        <<<dim3(1, 32, 16), blk, 0, stream>>>(
            SC, Vt + bQK, nullptr, At + bQK, Lb,
            2048, 2048, 2048, 1024, 1.f, 4194304LL, 131072LL, 64LL);
  }

  // output projection (BK=64) -> f32 d_out
  gemm_nt<128, 128, 64, false, true, true, false><<<dim3(8, 32, 1), blk, 0, stream>>>(
      At, Wob, bo, d_out, nullptr, 1024, 1024, 1024, 1024, 1.f, 0, 0, 0);
}

// Round 10
// 407.812 us; speedup vs baseline: 1.0372x; 1.0094x over previous
//
#include <hip/hip_runtime.h>

typedef unsigned short u16;
typedef unsigned int u32;
typedef short short8 __attribute__((ext_vector_type(8)));
typedef unsigned short ushort8 __attribute__((ext_vector_type(8)));
typedef unsigned short bf16x4 __attribute__((ext_vector_type(4)));
typedef float f32x4 __attribute__((ext_vector_type(4)));

#define DEVINL __device__ __forceinline__

DEVINL float bf2f(u16 u) {
  unsigned int x = ((unsigned int)u) << 16;
  return __builtin_bit_cast(float, x);
}
DEVINL u16 f2bf(float f) {
  unsigned int x = __builtin_bit_cast(unsigned int, f);
  x += 0x7FFFu + ((x >> 16) & 1u);  // RNE
  return (u16)(x >> 16);
}

// Async global->LDS, 16B per lane. LDS dest must be the WAVE-UNIFORM base
// (HW adds lane*16). Global src is per-lane.
DEVINL void ld16_lds(const u16* g, u16* l) {
  __builtin_amdgcn_global_load_lds(
      (const __attribute__((address_space(1))) u32*)(const void*)g,
      (__attribute__((address_space(3))) u32*)(void*)l, 16, 0, 0);
}

// Problem constants: B=2, S=2048, E=1024, H=16, DH=64
// r1: conv_softmax epilogue via LDS bounce -> coalesced dwordx4 (85 us).
// r2: stage-transpose static unrolled writes (75 us, VALUBusy 47->28).
// r3: [q][h][k] SC layout — REVERTED (neutral on conv, -7us on QK/PV).
// r4: gemm_qkv global_load_lds staging — kept (+2 us; qkv not staging-bound).
// r5 (this): conv_softmax single-pass: rawT stride 24->16 u16, one 2048-k
// segment (all loads in flight together, 3 fewer barriers, one MFMA phase).
// Cost: b-frag reads ~8-way banked (stride-32B rows) — accepted per m136.

// ---------------------------------------------------------------------------
// Fused f32 -> bf16 conversion of query + 4 weight matrices.
// ---------------------------------------------------------------------------
__global__ __launch_bounds__(256) void cvt_all(
    const float* __restrict__ q, const float* __restrict__ wq,
    const float* __restrict__ wk, const float* __restrict__ wv,
    const float* __restrict__ wo, u16* __restrict__ out) {
  int i = blockIdx.x * 256 + threadIdx.x;  // < 1048576
  const float* src;
  size_t off8;
  if (i < 524288) { src = q;  off8 = i; }
  else if (i < 655360) { src = wq; off8 = i - 524288; }
  else if (i < 786432) { src = wk; off8 = i - 655360; }
  else if (i < 917504) { src = wv; off8 = i - 786432; }
  else { src = wo; off8 = i - 917504; }
  f32x4 a = ((const f32x4*)src)[2 * off8];
  f32x4 b = ((const f32x4*)src)[2 * off8 + 1];
  ushort8 o;
#pragma unroll
  for (int e = 0; e < 4; ++e) o[e] = f2bf(a[e]);
#pragma unroll
  for (int e = 0; e < 4; ++e) o[4 + e] = f2bf(b[e]);
  ((ushort8*)out)[i] = o;
}

// ---------------------------------------------------------------------------
// NT GEMM (bf16 in via MFMA): C[i,j] = scale * sum_k A[i,k]*B[j,k] (+ bias[j])
// BK: K-tile (32 or 64). RSCALE: multiply row i of batch z by rsc[z*2048+i].
// ---------------------------------------------------------------------------
template <int BM, int BN, int BK, bool TRANSV, bool HASBIAS, bool OUTF32,
          bool RSCALE>
__global__ __launch_bounds__(256) void gemm_nt(
    const u16* __restrict__ A, const u16* __restrict__ Bm,
    const float* __restrict__ bias, void* __restrict__ C,
    const float* __restrict__ rsc,
    int K, int lda, int ldb, int ldc, float scale,
    long long sAh, long long sBh, long long sCh) {
  constexpr int LDSS = BK + 8;       // padded LDS row stride (u16)
  constexpr int KC8 = BK / 8;        // 8-elem groups per row
  constexpr int KSH = (BK == 32) ? 2 : 3;
  constexpr int WM = BM / 2, WN = BN / 2, FM = WM / 16, FN = WN / 16;
  constexpr int AIN = BM * KC8 / 256;
  constexpr int BIN = BN * KC8 / 256;

  __shared__ alignas(16) u16 As[BM * LDSS];
  __shared__ alignas(16) u16 Bs[BN * LDSS];

  const int tid = threadIdx.x;
  const int lane = tid & 63;
  const int wv = tid >> 6;
  const int wy = wv >> 1, wx = wv & 1;
  const int quad = lane >> 4, mrow = lane & 15;

  const int z = blockIdx.z;
  const u16* Ap = A + z * sAh;
  const u16* Bp = Bm + z * sBh;
  u16* Cp = (u16*)C + z * sCh;
  float* Cf = (float*)C + z * sCh;

  const int row0 = blockIdx.y * BM;
  const int col0 = blockIdx.x * BN;

  f32x4 acc[FM][FN];
#pragma unroll
  for (int i = 0; i < FM; ++i)
#pragma unroll
    for (int j = 0; j < FN; ++j) acc[i][j] = f32x4{0.f, 0.f, 0.f, 0.f};

  for (int k0 = 0; k0 < K; k0 += BK) {
    ushort8 ta[AIN], tb[BIN];
#pragma unroll
    for (int r = 0; r < AIN; ++r) {
      int idx = r * 256 + tid;
      int row = idx >> KSH, ch = idx & (KC8 - 1);
      ta[r] = *(const ushort8*)(Ap + (size_t)(row0 + row) * lda + k0 + ch * 8);
    }
#pragma unroll
    for (int r = 0; r < BIN; ++r) {
      int idx = r * 256 + tid;
      int row = idx >> KSH, ch = idx & (KC8 - 1);
      tb[r] = *(const ushort8*)(Bp + (size_t)(col0 + row) * ldb + k0 + ch * 8);
    }
    __syncthreads();  // previous iteration's LDS reads done
#pragma unroll
    for (int r = 0; r < AIN; ++r) {
      int idx = r * 256 + tid;
      int row = idx >> KSH, ch = idx & (KC8 - 1);
      *(ushort8*)&As[row * LDSS + ch * 8] = ta[r];
    }
#pragma unroll
    for (int r = 0; r < BIN; ++r) {
      int idx = r * 256 + tid;
      int row = idx >> KSH, ch = idx & (KC8 - 1);
      *(ushort8*)&Bs[row * LDSS + ch * 8] = tb[r];
    }
    __syncthreads();

#pragma unroll
    for (int ks = 0; ks < BK / 32; ++ks) {
      short8 af[FM], bfr[FN];
#pragma unroll
      for (int mi = 0; mi < FM; ++mi)
        af[mi] = *(const short8*)&As[(wy * WM + mi * 16 + mrow) * LDSS + ks * 32 + quad * 8];
#pragma unroll
      for (int ni = 0; ni < FN; ++ni)
        bfr[ni] = *(const short8*)&Bs[(wx * WN + ni * 16 + mrow) * LDSS + ks * 32 + quad * 8];
#pragma unroll
      for (int mi = 0; mi < FM; ++mi)
#pragma unroll
        for (int ni = 0; ni < FN; ++ni)
          acc[mi][ni] = __builtin_amdgcn_mfma_f32_16x16x32_bf16(
              af[mi], bfr[ni], acc[mi][ni], 0, 0, 0);
    }
  }

  // Epilogue. C/D layout: col = lane&15, row = quad*4 + r  [m89/m91 verified]
#pragma unroll
  for (int mi = 0; mi < FM; ++mi) {
    const int rowb = row0 + wy * WM + mi * 16 + quad * 4;
#pragma unroll
    for (int ni = 0; ni < FN; ++ni) {
      const int col = col0 + wx * WN + ni * 16 + mrow;
      float bv = 0.f;
      if (HASBIAS) bv = bias[col];
      f32x4 v = acc[mi][ni];
      if (OUTF32) {
#pragma unroll
        for (int r = 0; r < 4; ++r)
          Cf[(size_t)(rowb + r) * ldc + col] = v[r] * scale + bv;
      } else if (!TRANSV) {
#pragma unroll
        for (int r = 0; r < 4; ++r) {
          float rs = 1.f;
          if (RSCALE) rs = rsc[(size_t)z * 2048 + rowb + r];
          Cp[(size_t)(rowb + r) * ldc + col] = f2bf(v[r] * scale * rs + bv);
        }
      } else {
        // Ct[b][col][s], per-batch stride E*S = 2097152
        const int bb = rowb >> 11;
        const int ss = rowb & 2047;
        bf16x4 pk;
#pragma unroll
        for (int r = 0; r < 4; ++r) pk[r] = f2bf(v[r] * scale + bv);
        *(bf16x4*)(Cp + (size_t)bb * 2097152 + (size_t)col * 2048 + ss) = pk;
      }
    }
  }
}

// ---------------------------------------------------------------------------
// Fused QKV projection: A = Qb [4096 x 1024], B = Wq|Wk|Wv rows [3072 x 1024].
// col part (block-uniform, BN=128): 0 -> Qw, 1 -> Kw, 2 -> Vt (transposed
// store Vt[b][e][s]). BK=64, BM=BN=128.
// r4: staging via global_load_lds (16B/lane), linear LDS [128][64] u16 with
// XOR swizzle: LDS 16B-slot s of row r holds global col-bytes (s^(r&7))*16;
// read applies byte ^= ((row&7)<<4). Same involution both sides (rule #21).
// ---------------------------------------------------------------------------
__global__ __launch_bounds__(256) void gemm_qkv(
    const u16* __restrict__ A, const u16* __restrict__ Bm,
    const float* __restrict__ bq, const float* __restrict__ bk,
    const float* __restrict__ bv,
    u16* __restrict__ Qw, u16* __restrict__ Kw, u16* __restrict__ Vt) {
  __shared__ alignas(16) u16 As[128 * 64];
  __shared__ alignas(16) u16 Bs[128 * 64];

  const int tid = threadIdx.x;
  const int lane = tid & 63;
  const int wv = tid >> 6;           // wave 0..3
  const int wy = wv >> 1, wx = wv & 1;
  const int quad = lane >> 4, mrow = lane & 15;

  const int row0 = blockIdx.y * 128;
  const int col0 = blockIdx.x * 128;

  // staging geometry: chunk = 1 KiB = 8 rows; lane covers (row srow, slot)
  const int srow = lane >> 3;                    // 0..7 within chunk
  const int scol = ((lane & 7) ^ srow) << 4;     // inverse-swizzled byte col

  f32x4 acc[4][4];
#pragma unroll
  for (int i = 0; i < 4; ++i)
#pragma unroll
    for (int j = 0; j < 4; ++j) acc[i][j] = f32x4{0.f, 0.f, 0.f, 0.f};

  for (int k0 = 0; k0 < 1024; k0 += 64) {
    __syncthreads();  // previous iteration's LDS reads done
#pragma unroll
    for (int i = 0; i < 4; ++i) {
      const int chunk = i * 4 + wv;              // 0..15
      const int row = chunk * 8 + srow;
      ld16_lds(A + (size_t)(row0 + row) * 1024 + k0 + (scol >> 1),
               &As[chunk * 512]);
      ld16_lds(Bm + (size_t)(col0 + row) * 1024 + k0 + (scol >> 1),
               &Bs[chunk * 512]);
    }
    __syncthreads();  // drains vmcnt(0): staged data visible

#pragma unroll
    for (int ks = 0; ks < 2; ++ks) {
      short8 af[4], bfr[4];
      const int cb = ks * 64 + quad * 16;        // byte col of frag
#pragma unroll
      for (int mi = 0; mi < 4; ++mi) {
        const int rowA = wy * 64 + mi * 16 + mrow;
        af[mi] = *(const short8*)&As[rowA * 64 + ((cb ^ ((rowA & 7) << 4)) >> 1)];
      }
#pragma unroll
      for (int ni = 0; ni < 4; ++ni) {
        const int rowB = wx * 64 + ni * 16 + mrow;
        bfr[ni] = *(const short8*)&Bs[rowB * 64 + ((cb ^ ((rowB & 7) << 4)) >> 1)];
      }
#pragma unroll
      for (int mi = 0; mi < 4; ++mi)
#pragma unroll
        for (int ni = 0; ni < 4; ++ni)
          acc[mi][ni] = __builtin_amdgcn_mfma_f32_16x16x32_bf16(
              af[mi], bfr[ni], acc[mi][ni], 0, 0, 0);
    }
  }

  const int part = col0 >> 10;  // 0:Q 1:K 2:V (block-uniform)
  const float* bias = (part == 0) ? bq : (part == 1) ? bk : bv;
#pragma unroll
  for (int mi = 0; mi < 4; ++mi) {
    const int rowb = row0 + wy * 64 + mi * 16 + quad * 4;
#pragma unroll
    for (int ni = 0; ni < 4; ++ni) {
      const int col = col0 + wx * 64 + ni * 16 + mrow;
      const int cl = col & 1023;
      const float bvl = bias[cl];
      f32x4 v = acc[mi][ni];
      if (part == 0) {
#pragma unroll
        for (int r = 0; r < 4; ++r)
          Qw[(size_t)(rowb + r) * 1024 + cl] = f2bf(v[r] + bvl);
      } else if (part == 1) {
#pragma unroll
        for (int r = 0; r < 4; ++r)
          Kw[(size_t)(rowb + r) * 1024 + cl] = f2bf(v[r] + bvl);
      } else {
        const int bb = rowb >> 11;
        const int ss = rowb & 2047;
        bf16x4 pk;
#pragma unroll
        for (int r = 0; r < 4; ++r) pk[r] = f2bf(v[r] + bvl);
        *(bf16x4*)(Vt + (size_t)bb * 2097152 + (size_t)cl * 2048 + ss) = pk;
      }
    }
  }
}

// ---------------------------------------------------------------------------
// MFMA cross-head conv1d (KS=3, zero pad) + softmax over key axis, in place.
// SC layout [h][q][k]. Writes UNNORMALIZED exp(x-M), emits 1/l to Lb.
// conv_b skipped: constant along softmax (k) axis -> cancels exactly.
// r5: SINGLE-PASS: rawT[k+1][h] stride 16 u16 for all 2048 k (+2 halo rows),
// one stage phase (8 loads/thread all in flight), one barrier, one MFMA
// phase (16 tiles/wave), then softmax + LDS-bounce writeback (P overlay
// stride 2064, k ^= quad<<4 — r1 scheme). LDS ~67 KB -> 2 blocks/CU.
// ---------------------------------------------------------------------------
__global__ __launch_bounds__(512, 2) void conv_softmax(
    u16* __restrict__ SC, const float* __restrict__ cw, float* __restrict__ Lb) {
  __shared__ alignas(16) u16 rawT[33024];  // union: 2050x16 transpose / 16x2064 P
  __shared__ float redA[8][16];
  __shared__ float redB[8][16];

  const int tid = threadIdx.x;
  const int lane = tid & 63;
  const int wv = tid >> 6;
  const int q = blockIdx.x;
  const int n = lane & 15;     // MFMA N-index = k-position within tile
  const int quad = lane >> 4;

  // A-frags (conv weights): lane's M-row h = n; kdim = quad*8+j -> (i,d)
  short8 a1, a2;
#pragma unroll
  for (int j = 0; j < 8; ++j) {
    const int kd = quad * 8 + j;
    const int i = kd & 15, d = kd >> 4;
    a1[j] = (short)f2bf(cw[n * 48 + i * 3 + d]);
    a2[j] = (quad < 2) ? (short)f2bf(cw[n * 48 + kd * 3 + 2]) : (short)0;
  }

  f32x4 acc[16];
#pragma unroll
  for (int ai = 0; ai < 16; ++ai) acc[ai] = f32x4{0.f, 0.f, 0.f, 0.f};

  {  // single transpose-load of all 2048 k into rawT[k+1][h] (stride 16)
    const int h = tid & 15, kc = tid >> 4;  // kc in [0,32)
    const size_t rowbase = ((size_t)h * 2048 + q) * 2048;
#pragma unroll
    for (int j = 0; j < 8; ++j) {
      const int kb = kc * 64 + j * 8;
      ushort8 v = *(const ushort8*)&SC[rowbase + kb];
      u16* dst = &rawT[(kb + 1) * 16 + h];
#pragma unroll
      for (int e = 0; e < 8; ++e) dst[e * 16] = v[e];
    }
    if (tid < 32) {  // halo rows: k = -1 (row 0) and k = 2048 (row 2049)
      const int h2 = tid & 15;
      const int top = tid >> 4;
      const int k = top ? 2048 : -1;
      u16 val = 0;
      if ((unsigned)k < 2048u) val = SC[((size_t)h2 * 2048 + q) * 2048 + k];
      rawT[(top ? 2049 : 0) * 16 + h2] = val;
    }
  }
  __syncthreads();

#pragma unroll
  for (int tt = 0; tt < 16; ++tt) {
    const int k0l = (wv * 16 + tt) * 16;  // local k of tile start
    const short8 b1 = *(const short8*)&rawT[(k0l + n + (quad >> 1)) * 16 + (quad & 1) * 8];
    const short8 b2 = *(const short8*)&rawT[(k0l + n + 2) * 16 + (quad & 1) * 8];
    acc[tt] = __builtin_amdgcn_mfma_f32_16x16x32_bf16(a1, b1, acc[tt], 0, 0, 0);
    acc[tt] = __builtin_amdgcn_mfma_f32_16x16x32_bf16(a2, b2, acc[tt], 0, 0, 0);
  }

  // ---- softmax over k per head (head = quad*4 + r) ----
  float fm[4];
#pragma unroll
  for (int r = 0; r < 4; ++r) fm[r] = -3e38f;
#pragma unroll
  for (int ai = 0; ai < 16; ++ai)
#pragma unroll
    for (int r = 0; r < 4; ++r) fm[r] = fmaxf(fm[r], acc[ai][r]);
#pragma unroll
  for (int off = 1; off < 16; off <<= 1)
#pragma unroll
    for (int r = 0; r < 4; ++r) fm[r] = fmaxf(fm[r], __shfl_xor(fm[r], off));
  if (n == 0)
#pragma unroll
    for (int r = 0; r < 4; ++r) redA[wv][quad * 4 + r] = fm[r];
  __syncthreads();  // also: all rawT MFMA reads done -> P overlay safe after
#pragma unroll
  for (int r = 0; r < 4; ++r) {
    float m = redA[0][quad * 4 + r];
#pragma unroll
    for (int w = 1; w < 8; ++w) m = fmaxf(m, redA[w][quad * 4 + r]);
    fm[r] = m;
  }
  float fs[4] = {0.f, 0.f, 0.f, 0.f};
#pragma unroll
  for (int ai = 0; ai < 16; ++ai)
#pragma unroll
    for (int r = 0; r < 4; ++r) {
      acc[ai][r] = __expf(acc[ai][r] - fm[r]);
      fs[r] += acc[ai][r];
    }
#pragma unroll
  for (int off = 1; off < 16; off <<= 1)
#pragma unroll
    for (int r = 0; r < 4; ++r) fs[r] += __shfl_xor(fs[r], off);
  if (n == 0)
#pragma unroll
    for (int r = 0; r < 4; ++r) redB[wv][quad * 4 + r] = fs[r];
  __syncthreads();
  // 1/l -> Lb (normalization applied in PV epilogue)
  if (wv == 0 && n == 0) {
#pragma unroll
    for (int r = 0; r < 4; ++r) {
      float sum = 0.f;
#pragma unroll
      for (int w = 0; w < 8; ++w) sum += redB[w][quad * 4 + r];
      Lb[(size_t)(quad * 4 + r) * 2048 + q] = 1.f / sum;
    }
  }

  // ---- write back unnormalized exp (bf16, in place), via LDS bounce ----
  // rawT dead after redA barrier; overlay P[h][k], stride 2064 (row dword-
  // offset ≡ 8 mod 32), k XOR quad<<4 -> 4 quads on disjoint 8-bank groups.
  // Read side applies the same XOR (involution, rule #21).
  u16* Pl = rawT;
  const int hst = tid >> 5;            // store-phase head (16 heads x 32 thr)
  const int kst = (tid & 31) * 8;      // store-phase k-group base
  const int xst = (hst >> 2) << 4;     // read-side XOR = quad(h)<<4
#pragma unroll
  for (int tt = 0; tt < 16; ++tt) {
    const int kl = (wv * 16 + tt) * 16 + n;
#pragma unroll
    for (int r = 0; r < 4; ++r) {
      const int h = quad * 4 + r;
      Pl[h * 2064 + (kl ^ (quad << 4))] = f2bf(acc[tt][r]);
    }
  }
  __syncthreads();
#pragma unroll
  for (int p = 0; p < 8; ++p) {
    const int kg = p * 256 + kst;
    ushort8 v = *(const ushort8*)&Pl[hst * 2064 + (kg ^ xst)];
    *(ushort8*)&SC[((size_t)hst * 2048 + q) * 2048 + kg] = v;
  }
}

// Diagnostic: fill f32 output with 2000.0 (ws-too-small marker).
__global__ void fill_diag(float* out, int n) {
  int i = blockIdx.x * 256 + threadIdx.x;
  if (i < n) out[i] = 2000.0f;
}

extern "C" void kernel_launch(void* const* d_in, const int* in_sizes, int n_in,
                              void* d_out, int out_size, void* d_ws, size_t ws_size,
                              hipStream_t stream) {
  const float* query = (const float*)d_in[0];
  const float* Wq = (const float*)d_in[1];
  const float* bq = (const float*)d_in[2];
  const float* Wk = (const float*)d_in[3];
  const float* bk = (const float*)d_in[4];
  const float* Wv = (const float*)d_in[5];
  const float* bv = (const float*)d_in[6];
  const float* Wo = (const float*)d_in[7];
  const float* bo = (const float*)d_in[8];
  const float* cw = (const float*)d_in[9];
  // d_in[10] (conv_b) intentionally unused: cancels in softmax.

  const size_t SE = (size_t)4096 * 1024;  // B*S*E elems
  const size_t WE = (size_t)1024 * 1024;  // E*E elems
  const size_t SCE = (size_t)16 * 2048 * 2048;  // per-batch scores elems
  const size_t fixedB = ((SE + 4 * WE) + 4 * SE) * sizeof(u16);  // 48 MiB
  const size_t LBB = (size_t)16 * 2048 * sizeof(float);          // 128 KiB
  if (ws_size < fixedB + SCE * sizeof(u16) + LBB) {
    fill_diag<<<dim3((out_size + 255) / 256), dim3(256), 0, stream>>>(
        (float*)d_out, out_size);
    return;
  }

  u16* ws = (u16*)d_ws;
  u16* Qb = ws;              // bf16 query [b][s][e]
  u16* Wqb = Qb + SE;        // bf16 weights (contiguous: Wq|Wk|Wv|Wo)
  u16* Wkb = Wqb + WE;
  u16* Wvb = Wkb + WE;
  u16* Wob = Wvb + WE;
  u16* Qw = Wob + WE;        // [b][s][e]
  u16* Kw = Qw + SE;         // [b][s][e]
  u16* Vt = Kw + SE;         // [b][e][s] transposed V
  u16* At = Vt + SE;         // attention output [b][s][e] (bf16)
  u16* SC = At + SE;         // scores (one batch) [h][q][k]
  float* Lb = (float*)(SC + SCE);  // inverse softmax sums [h][q]

  dim3 blk(256);
  cvt_all<<<dim3(4096), blk, 0, stream>>>(query, Wq, Wk, Wv, Wo, Qb);

  // Fused Q/K/V projection (BK=64): B rows = Wqb|Wkb|Wvb (3072 x 1024)
  gemm_qkv<<<dim3(24, 32, 1), blk, 0, stream>>>(
      Qb, Wqb, bq, bk, bv, Qw, Kw, Vt);

  for (int b = 0; b < 2; ++b) {
    const size_t bQK = (size_t)b * 2097152;
    // raw scores = Q Kh^T / 8 per head: M=N=2048, K=64 (BK=64, single stage)
    gemm_nt<128, 128, 64, false, false, false, false>
        <<<dim3(16, 16, 16), blk, 0, stream>>>(
            Qw + bQK, Kw + bQK, nullptr, SC, nullptr,
            64, 1024, 1024, 2048, 0.125f, 64LL, 64LL, 4194304LL);
    // conv + softmax (unnormalized P + 1/l into Lb)
    conv_softmax<<<dim3(2048), dim3(512), 0, stream>>>(SC, cw, Lb);
    // PV: M=2048 (q), N=64 (d), K=2048 per head (BK=64); epilogue applies 1/l
    gemm_nt<64, 64, 64, false, false, false, true>
        <<<dim3(1, 32, 16), blk, 0, stream>>>(
            SC, Vt + bQK, nullptr, At + bQK, Lb,
            2048, 2048, 2048, 1024, 1.f, 4194304LL, 131072LL, 64LL);
  }

  // output projection (BK=64) -> f32 d_out
  gemm_nt<128, 128, 64, false, true, true, false><<<dim3(8, 32, 1), blk, 0, stream>>>(
      At, Wob, bo, d_out, nullptr, 1024, 1024, 1024, 1024, 1.f, 0, 0, 0);
}